// Round 5
// baseline (261.039 us; speedup 1.0000x reference)
//
#include <hip/hip_runtime.h>
#include <hip/hip_fp16.h>
#include <math.h>

// ChebConv (K=4) GNN head. N=50000, E=800000, F_IN=64, H=128.
// R5: XCD-split SPMM (each block gathers a 64B feature-half so per-XCD L2
// working set = 3.2MB < 4MiB), 2 edge-subgroups per row (8 outstanding
// gathers), MFMA GEMM unchanged.

#define FIN 64
#define HDIM 128

typedef _Float16 half8 __attribute__((ext_vector_type(8)));
typedef float f32x4 __attribute__((ext_vector_type(4)));

union U16 { uint4 u; __half2 h2[4]; half8 h8; };

__global__ void count_deg(const int* __restrict__ row, int* __restrict__ deg, int E) {
    int e = blockIdx.x * blockDim.x + threadIdx.x;
    if (e < E) atomicAdd(&deg[row[e]], 1);
}

__global__ void make_dinv(const int* __restrict__ deg, float* __restrict__ dinv, int n) {
    int i = blockIdx.x * blockDim.x + threadIdx.x;
    if (i < n) {
        int d = deg[i];
        dinv[i] = (d > 0) ? rsqrtf((float)d) : 0.f;
    }
}

// features fp32 -> fp16 rows
__global__ void cvt_feat(const float4* __restrict__ src, uint4* __restrict__ dst, int n8) {
    int i = blockIdx.x * blockDim.x + threadIdx.x;
    if (i >= n8) return;
    float4 a = src[i * 2], b = src[i * 2 + 1];
    U16 v;
    v.h2[0] = __float22half2_rn(make_float2(a.x, a.y));
    v.h2[1] = __float22half2_rn(make_float2(a.z, a.w));
    v.h2[2] = __float22half2_rn(make_float2(b.x, b.y));
    v.h2[3] = __float22half2_rn(make_float2(b.z, b.w));
    dst[i] = v.u;
}

// Pre-swizzle cheb_w (viewed as B[256 k][128 h] fp32) into per-lane MFMA
// B-fragment order: Bfrag[(kk*8+ht)*64+lane] = 8 halfs B[kk*32+(lane>>4)*8+j][ht*16+(lane&15)]
__global__ void make_bfrag(const float* __restrict__ W, uint4* __restrict__ bfrag) {
    int t = blockIdx.x * blockDim.x + threadIdx.x;   // 0..4095
    if (t >= 8 * 8 * 64) return;
    int lane = t & 63;
    int ht = (t >> 6) & 7;
    int kk = t >> 9;
    int h = ht * 16 + (lane & 15);
    int kb = kk * 32 + (lane >> 4) * 8;
    U16 v;
#pragma unroll
    for (int j = 0; j < 4; ++j) {
        float a = W[(kb + 2 * j) * HDIM + h];
        float b = W[(kb + 2 * j + 1) * HDIM + h];
        v.h2[j] = __float22half2_rn(make_float2(a, b));
    }
    bfrag[t] = v.u;
}

// Per-block exclusive scan (Hillis-Steele over 1024 elems) + block totals.
__global__ void scan_local(const int* __restrict__ in, int* __restrict__ out,
                           int* __restrict__ bsum, int n) {
    __shared__ int buf[1024];
    int tid = threadIdx.x;
    int gid = blockIdx.x * 1024 + tid;
    int v = (gid < n) ? in[gid] : 0;
    int x = v;
    buf[tid] = x;
    __syncthreads();
    for (int off = 1; off < 1024; off <<= 1) {
        int t = (tid >= off) ? buf[tid - off] : 0;
        __syncthreads();
        x += t;
        buf[tid] = x;
        __syncthreads();
    }
    if (gid < n) out[gid] = x - v;
    if (tid == 1023) bsum[blockIdx.x] = x;
}

__global__ void scan_bsums(int* bsum, int nb) {
    if (blockIdx.x == 0 && threadIdx.x == 0) {
        int acc = 0;
        for (int b = 0; b < nb; ++b) { int t = bsum[b]; bsum[b] = acc; acc += t; }
    }
}

__global__ void scan_finish(int* __restrict__ rowptr, const int* __restrict__ bsum,
                            int* __restrict__ cursor, int n, int E) {
    int i = blockIdx.x * blockDim.x + threadIdx.x;
    if (i < n) {
        int v = rowptr[i] + bsum[i >> 10];
        rowptr[i] = v;
        cursor[i] = v;
    } else if (i == n) {
        rowptr[n] = E;
    }
}

__global__ void scatter_edges(const int* __restrict__ row, const int* __restrict__ col,
                              const float* __restrict__ dinv, int* __restrict__ cursor,
                              int2* __restrict__ epk, int E) {
    int e = blockIdx.x * blockDim.x + threadIdx.x;
    if (e < E) {
        int r = row[e], c = col[e];
        int p = atomicAdd(&cursor[r], 1);
        float w = -dinv[r] * dinv[c];   // L_hat = -D^-1/2 A D^-1/2
        epk[p] = make_int2(c, __float_as_int(w));
    }
}

// XCD-split SPMM. Grid = 2x; half = blockIdx&1 picks the 64B feature-half.
// Wave = 8 rows x (2 edge-subgroups x 4 lanes x 16B). fp32 accumulate.
// Subgroups walk disjoint halves of the row's edge list (unroll 4 = 8
// outstanding gathers/row), combined via shfl_xor(4); sub==0 lanes store.
__global__ __launch_bounds__(256) void spmm_h(
        const int* __restrict__ rowptr, const int2* __restrict__ epk,
        const uint4* __restrict__ in8, const uint4* __restrict__ prev8,
        float scale, uint4* __restrict__ out8, int n) {
    int half = blockIdx.x & 1;
    int bid = blockIdx.x >> 1;
    int tid = threadIdx.x;
    int lane = tid & 63;
    int wave = bid * 4 + (tid >> 6);
    int g = lane >> 3;              // row subgroup 0..7
    int sub = (lane >> 2) & 1;      // edge-list half
    int li = lane & 3;              // 16B chunk within 64B feature-half
    int r = wave * 8 + g;
    if (r >= n) return;
    int s = rowptr[r], e = rowptr[r + 1];
    int mid = s + ((e - s + 1) >> 1);
    int p = sub ? mid : s;
    int pe = sub ? e : mid;
    int fo = half * 4 + li;         // uint4 offset within the 128B row

    float acc[8];
#pragma unroll
    for (int j = 0; j < 8; ++j) acc[j] = 0.f;

    for (; p + 4 <= pe; p += 4) {
        int2 m0 = epk[p], m1 = epk[p + 1], m2 = epk[p + 2], m3 = epk[p + 3];
        U16 v0, v1, v2, v3;
        v0.u = in8[(size_t)m0.x * 8 + fo];
        v1.u = in8[(size_t)m1.x * 8 + fo];
        v2.u = in8[(size_t)m2.x * 8 + fo];
        v3.u = in8[(size_t)m3.x * 8 + fo];
        float w0 = __int_as_float(m0.y), w1 = __int_as_float(m1.y);
        float w2 = __int_as_float(m2.y), w3 = __int_as_float(m3.y);
#pragma unroll
        for (int j = 0; j < 4; ++j) {
            float2 f0 = __half22float2(v0.h2[j]);
            float2 f1 = __half22float2(v1.h2[j]);
            float2 f2 = __half22float2(v2.h2[j]);
            float2 f3 = __half22float2(v3.h2[j]);
            acc[2 * j]     = fmaf(w0, f0.x, acc[2 * j]);
            acc[2 * j + 1] = fmaf(w0, f0.y, acc[2 * j + 1]);
            acc[2 * j]     = fmaf(w1, f1.x, acc[2 * j]);
            acc[2 * j + 1] = fmaf(w1, f1.y, acc[2 * j + 1]);
            acc[2 * j]     = fmaf(w2, f2.x, acc[2 * j]);
            acc[2 * j + 1] = fmaf(w2, f2.y, acc[2 * j + 1]);
            acc[2 * j]     = fmaf(w3, f3.x, acc[2 * j]);
            acc[2 * j + 1] = fmaf(w3, f3.y, acc[2 * j + 1]);
        }
    }
    for (; p < pe; ++p) {
        int2 m0 = epk[p];
        U16 v0;
        v0.u = in8[(size_t)m0.x * 8 + fo];
        float w0 = __int_as_float(m0.y);
#pragma unroll
        for (int j = 0; j < 4; ++j) {
            float2 f0 = __half22float2(v0.h2[j]);
            acc[2 * j]     = fmaf(w0, f0.x, acc[2 * j]);
            acc[2 * j + 1] = fmaf(w0, f0.y, acc[2 * j + 1]);
        }
    }
    // combine the two edge-subgroups (lane ^ 4)
#pragma unroll
    for (int j = 0; j < 8; ++j) acc[j] += __shfl_xor(acc[j], 4, 64);

    if (sub == 0) {
        if (prev8) {
            U16 pv;
            pv.u = prev8[(size_t)r * 8 + fo];
#pragma unroll
            for (int j = 0; j < 4; ++j) {
                float2 f = __half22float2(pv.h2[j]);
                acc[2 * j]     = fmaf(scale, acc[2 * j], -f.x);
                acc[2 * j + 1] = fmaf(scale, acc[2 * j + 1], -f.y);
            }
        } else {
#pragma unroll
            for (int j = 0; j < 8; ++j) acc[j] *= scale;
        }
        U16 res;
#pragma unroll
        for (int j = 0; j < 4; ++j)
            res.h2[j] = __float22half2_rn(make_float2(acc[2 * j], acc[2 * j + 1]));
        out8[(size_t)r * 8 + fo] = res.u;
    }
}

__device__ inline float tanh_fast(float x) {
    x = fmaxf(-10.f, fminf(10.f, x));
    float e = __expf(2.f * x);
    return (e - 1.f) / (e + 1.f);
}

// MFMA GEMM + tanh + final dot. Block = 256 thr = 4 waves; wave = 16 nodes x
// 128 h (8 tiles of 16x16, K=32/step, 8 steps over K=256). LDS-free:
// A frag = one 16B global load; B frags pre-swizzled (64KB, L2-resident).
// C layout: col(h)=lane&15, row=q*4+reg.
__global__ __launch_bounds__(256) void gemm_mfma(
        const uint4* __restrict__ tx0, const uint4* __restrict__ tx1,
        const uint4* __restrict__ tx2, const uint4* __restrict__ tx3,
        const uint4* __restrict__ bfrag,
        const float* __restrict__ cheb_b, const float* __restrict__ fw,
        const float* __restrict__ fb, float* __restrict__ out, int n) {
    int tid = threadIdx.x;
    int lane = tid & 63;
    int wave = tid >> 6;
    int q = lane >> 4, m = lane & 15;
    int node_base = blockIdx.x * 64 + wave * 16;
    int node = node_base + m;
    size_t nd = (node < n) ? (size_t)node : 0;   // clamp; store is guarded

    f32x4 acc[8];
#pragma unroll
    for (int t = 0; t < 8; ++t) acc[t] = (f32x4){0.f, 0.f, 0.f, 0.f};

    const uint4* txs[4] = {tx0, tx1, tx2, tx3};
#pragma unroll
    for (int kk = 0; kk < 8; ++kk) {
        U16 av;
        av.u = txs[kk >> 1][nd * 8 + (kk & 1) * 4 + q];
#pragma unroll
        for (int ht = 0; ht < 8; ++ht) {
            U16 bv;
            bv.u = bfrag[(kk * 8 + ht) * 64 + lane];
            acc[ht] = __builtin_amdgcn_mfma_f32_16x16x32_f16(av.h8, bv.h8, acc[ht], 0, 0, 0);
        }
    }

    // epilogue: s[reg] = sum_h tanh(acc + cb[h]) * fw[h]; reduce over 16 lanes
    float s[4] = {0.f, 0.f, 0.f, 0.f};
#pragma unroll
    for (int ht = 0; ht < 8; ++ht) {
        int h = ht * 16 + m;
        float cb = cheb_b[h];
        float fv = fw[h];
#pragma unroll
        for (int r = 0; r < 4; ++r)
            s[r] = fmaf(tanh_fast(acc[ht][r] + cb), fv, s[r]);
    }
#pragma unroll
    for (int r = 0; r < 4; ++r) {
        for (int msk = 1; msk < 16; msk <<= 1)
            s[r] += __shfl_xor(s[r], msk, 64);
    }
    if (m == 0) {
        float fb0 = fb[0];
#pragma unroll
        for (int r = 0; r < 4; ++r) {
            int o = node_base + q * 4 + r;
            if (o < n) out[o] = s[r] + fb0;
        }
    }
}

extern "C" void kernel_launch(void* const* d_in, const int* in_sizes, int n_in,
                              void* d_out, int out_size, void* d_ws, size_t ws_size,
                              hipStream_t stream) {
    const float* features = (const float*)d_in[0];
    const int*   edge_index = (const int*)d_in[1];
    const float* cheb_w  = (const float*)d_in[2];
    const float* cheb_b  = (const float*)d_in[3];
    const float* final_w = (const float*)d_in[4];
    const float* final_b = (const float*)d_in[5];
    int N = in_sizes[0] / FIN;
    int E = in_sizes[1] / 2;
    const int* row = edge_index;        // edge_index[0, :]
    const int* col = edge_index + E;    // edge_index[1, :]

    char* p = (char*)d_ws;
    auto alloc = [&](size_t bytes) {
        char* r = p;
        p += (bytes + 255) & ~(size_t)255;
        return r;
    };
    int*   deg    = (int*)alloc((size_t)N * 4);
    float* dinv   = (float*)alloc((size_t)N * 4);
    int*   rowptr = (int*)alloc((size_t)(N + 1) * 4);
    int*   cursor = (int*)alloc((size_t)N * 4);
    int*   bsum   = (int*)alloc(1024 * 4);
    int2*  epk    = (int2*)alloc((size_t)E * 8);
    uint4* feath  = (uint4*)alloc((size_t)N * FIN * 2);   // fp16 rows
    uint4* tx1h   = (uint4*)alloc((size_t)N * FIN * 2);
    uint4* tx2h   = (uint4*)alloc((size_t)N * FIN * 2);
    uint4* tx3h   = (uint4*)alloc((size_t)N * FIN * 2);
    uint4* bfrag  = (uint4*)alloc(4096 * 16);             // 64 KB B fragments

    hipMemsetAsync(deg, 0, (size_t)N * 4, stream);
    count_deg<<<(E + 255) / 256, 256, 0, stream>>>(row, deg, E);
    make_dinv<<<(N + 255) / 256, 256, 0, stream>>>(deg, dinv, N);
    int n8 = N * FIN / 8;
    cvt_feat<<<(n8 + 255) / 256, 256, 0, stream>>>((const float4*)features, feath, n8);
    make_bfrag<<<16, 256, 0, stream>>>(cheb_w, bfrag);
    int nb = (N + 1023) / 1024;
    scan_local<<<nb, 1024, 0, stream>>>(deg, rowptr, bsum, N);
    scan_bsums<<<1, 64, 0, stream>>>(bsum, nb);
    scan_finish<<<(N + 1 + 255) / 256, 256, 0, stream>>>(rowptr, bsum, cursor, N, E);
    scatter_edges<<<(E + 255) / 256, 256, 0, stream>>>(row, col, dinv, cursor, epk, E);

    // 8 rows/wave, 4 waves/block => 32 rows/block; grid doubled for halves
    int blocks_per_half = (N + 31) / 32;
    int spmm_grid = blocks_per_half * 2;
    // Tx1 = L_hat @ x
    spmm_h<<<spmm_grid, 256, 0, stream>>>(rowptr, epk, feath, nullptr, 1.f, tx1h, N);
    // Tx2 = 2 * L_hat @ Tx1 - Tx0
    spmm_h<<<spmm_grid, 256, 0, stream>>>(rowptr, epk, tx1h, feath, 2.f, tx2h, N);
    // Tx3 = 2 * L_hat @ Tx2 - Tx1
    spmm_h<<<spmm_grid, 256, 0, stream>>>(rowptr, epk, tx2h, tx1h, 2.f, tx3h, N);

    gemm_mfma<<<(N + 63) / 64, 256, 0, stream>>>(feath, tx1h, tx2h, tx3h, bfrag,
                                                 cheb_b, final_w, final_b,
                                                 (float*)d_out, N);
}

// Round 6
// 257.443 us; speedup vs baseline: 1.0140x; 1.0140x over previous
//
#include <hip/hip_runtime.h>
#include <hip/hip_fp16.h>
#include <math.h>

// ChebConv (K=4) GNN head. N=50000, E=800000, F_IN=64, H=128.
// R6: weight-free SPMM via pre-scaled rows (xs = dinv*Tx), col-only edge
// array, row-striped 4-pass scatter for write locality. MFMA GEMM unchanged.

#define FIN 64
#define HDIM 128

typedef _Float16 half8 __attribute__((ext_vector_type(8)));
typedef float f32x4 __attribute__((ext_vector_type(4)));

union U16 { uint4 u; __half2 h2[4]; half8 h8; };

__global__ void count_deg(const int* __restrict__ row, int* __restrict__ deg, int E) {
    int e = blockIdx.x * blockDim.x + threadIdx.x;
    if (e < E) atomicAdd(&deg[row[e]], 1);
}

__global__ void make_dinv(const int* __restrict__ deg, float* __restrict__ dinv, int n) {
    int i = blockIdx.x * blockDim.x + threadIdx.x;
    if (i < n) {
        int d = deg[i];
        dinv[i] = (d > 0) ? rsqrtf((float)d) : 0.f;
    }
}

// features fp32 -> fp16 rows: unscaled (dsth, for GEMM/prev) + dinv-scaled
// (dsts, gather source). One uint4 (8 halves) per thread.
__global__ void cvt_feat(const float4* __restrict__ src, const float* __restrict__ dinv,
                         uint4* __restrict__ dsth, uint4* __restrict__ dsts, int n8) {
    int i = blockIdx.x * blockDim.x + threadIdx.x;
    if (i >= n8) return;
    float d = dinv[i >> 3];
    float4 a = src[i * 2], b = src[i * 2 + 1];
    U16 v, vs;
    v.h2[0] = __float22half2_rn(make_float2(a.x, a.y));
    v.h2[1] = __float22half2_rn(make_float2(a.z, a.w));
    v.h2[2] = __float22half2_rn(make_float2(b.x, b.y));
    v.h2[3] = __float22half2_rn(make_float2(b.z, b.w));
    vs.h2[0] = __float22half2_rn(make_float2(d * a.x, d * a.y));
    vs.h2[1] = __float22half2_rn(make_float2(d * a.z, d * a.w));
    vs.h2[2] = __float22half2_rn(make_float2(d * b.x, d * b.y));
    vs.h2[3] = __float22half2_rn(make_float2(d * b.z, d * b.w));
    dsth[i] = v.u;
    dsts[i] = vs.u;
}

// Pre-swizzle cheb_w (B[256 k][128 h] fp32) into per-lane MFMA B-fragments.
__global__ void make_bfrag(const float* __restrict__ W, uint4* __restrict__ bfrag) {
    int t = blockIdx.x * blockDim.x + threadIdx.x;   // 0..4095
    if (t >= 8 * 8 * 64) return;
    int lane = t & 63;
    int ht = (t >> 6) & 7;
    int kk = t >> 9;
    int h = ht * 16 + (lane & 15);
    int kb = kk * 32 + (lane >> 4) * 8;
    U16 v;
#pragma unroll
    for (int j = 0; j < 4; ++j) {
        float a = W[(kb + 2 * j) * HDIM + h];
        float b = W[(kb + 2 * j + 1) * HDIM + h];
        v.h2[j] = __float22half2_rn(make_float2(a, b));
    }
    bfrag[t] = v.u;
}

// Per-block exclusive scan (Hillis-Steele over 1024 elems) + block totals.
__global__ void scan_local(const int* __restrict__ in, int* __restrict__ out,
                           int* __restrict__ bsum, int n) {
    __shared__ int buf[1024];
    int tid = threadIdx.x;
    int gid = blockIdx.x * 1024 + tid;
    int v = (gid < n) ? in[gid] : 0;
    int x = v;
    buf[tid] = x;
    __syncthreads();
    for (int off = 1; off < 1024; off <<= 1) {
        int t = (tid >= off) ? buf[tid - off] : 0;
        __syncthreads();
        x += t;
        buf[tid] = x;
        __syncthreads();
    }
    if (gid < n) out[gid] = x - v;
    if (tid == 1023) bsum[blockIdx.x] = x;
}

__global__ void scan_bsums(int* bsum, int nb) {
    if (blockIdx.x == 0 && threadIdx.x == 0) {
        int acc = 0;
        for (int b = 0; b < nb; ++b) { int t = bsum[b]; bsum[b] = acc; acc += t; }
    }
}

__global__ void scan_finish(int* __restrict__ rowptr, const int* __restrict__ bsum,
                            int* __restrict__ cursor, int n, int E) {
    int i = blockIdx.x * blockDim.x + threadIdx.x;
    if (i < n) {
        int v = rowptr[i] + bsum[i >> 10];
        rowptr[i] = v;
        cursor[i] = v;
    } else if (i == n) {
        rowptr[n] = E;
    }
}

// Row-striped scatter pass: only rows in [r_lo, r_hi) are placed, so the
// write window (their CSR span) + cursors stay L2-resident.
__global__ void scatter_pass(const int* __restrict__ row, const int* __restrict__ col,
                             int* __restrict__ cursor, int* __restrict__ col_s,
                             int E, int r_lo, int r_hi) {
    int e = blockIdx.x * blockDim.x + threadIdx.x;
    if (e < E) {
        int r = row[e];
        if (r >= r_lo && r < r_hi) {
            int p = atomicAdd(&cursor[r], 1);
            col_s[p] = col[e];
        }
    }
}

// Weight-free SPMM. 8 rows/wave, 8 lanes/row, 16B (8 halves) per lane.
// acc = sum of pre-scaled gathered rows; res = -dinv[r]*two*acc - prev.
// Stores unscaled (outu) and, if needed, dinv-scaled (outs) for next gather.
__global__ __launch_bounds__(256) void spmm_g(
        const int* __restrict__ rowptr, const int* __restrict__ cols,
        const uint4* __restrict__ ins, const uint4* __restrict__ prevu,
        const float* __restrict__ dinv, float two,
        uint4* __restrict__ outu, uint4* __restrict__ outs, int n) {
    int lane = threadIdx.x & 63;
    int wid = (blockIdx.x * blockDim.x + threadIdx.x) >> 6;
    int li = lane & 7, g = lane >> 3;
    int r = wid * 8 + g;
    if (r >= n) return;
    int s = rowptr[r], e = rowptr[r + 1];
    float acc[8];
#pragma unroll
    for (int j = 0; j < 8; ++j) acc[j] = 0.f;
    int p = s;
    for (; p + 8 <= e; p += 8) {
        int c[8];
#pragma unroll
        for (int j = 0; j < 8; ++j) c[j] = cols[p + j];
        U16 v[8];
#pragma unroll
        for (int j = 0; j < 8; ++j) v[j].u = ins[(size_t)c[j] * 8 + li];
#pragma unroll
        for (int j = 0; j < 8; ++j) {
#pragma unroll
            for (int t = 0; t < 4; ++t) {
                float2 f = __half22float2(v[j].h2[t]);
                acc[2 * t] += f.x;
                acc[2 * t + 1] += f.y;
            }
        }
    }
    for (; p < e; ++p) {
        U16 v;
        v.u = ins[(size_t)cols[p] * 8 + li];
#pragma unroll
        for (int t = 0; t < 4; ++t) {
            float2 f = __half22float2(v.h2[t]);
            acc[2 * t] += f.x;
            acc[2 * t + 1] += f.y;
        }
    }
    float d = dinv[r];
    float rs = -d * two;
    float res[8];
    if (prevu) {
        U16 pv;
        pv.u = prevu[(size_t)r * 8 + li];
#pragma unroll
        for (int t = 0; t < 4; ++t) {
            float2 f = __half22float2(pv.h2[t]);
            res[2 * t]     = fmaf(rs, acc[2 * t], -f.x);
            res[2 * t + 1] = fmaf(rs, acc[2 * t + 1], -f.y);
        }
    } else {
#pragma unroll
        for (int j = 0; j < 8; ++j) res[j] = rs * acc[j];
    }
    U16 ru;
#pragma unroll
    for (int t = 0; t < 4; ++t)
        ru.h2[t] = __float22half2_rn(make_float2(res[2 * t], res[2 * t + 1]));
    outu[(size_t)r * 8 + li] = ru.u;
    if (outs) {
        U16 rsv;
#pragma unroll
        for (int t = 0; t < 4; ++t)
            rsv.h2[t] = __float22half2_rn(make_float2(d * res[2 * t], d * res[2 * t + 1]));
        outs[(size_t)r * 8 + li] = rsv.u;
    }
}

__device__ inline float tanh_fast(float x) {
    x = fmaxf(-10.f, fminf(10.f, x));
    float e = __expf(2.f * x);
    return (e - 1.f) / (e + 1.f);
}

// MFMA GEMM + tanh + final dot. Block = 256 thr = 4 waves; wave = 16 nodes x
// 128 h (8 tiles of 16x16, K=32/step, 8 steps over K=256). LDS-free.
__global__ __launch_bounds__(256) void gemm_mfma(
        const uint4* __restrict__ tx0, const uint4* __restrict__ tx1,
        const uint4* __restrict__ tx2, const uint4* __restrict__ tx3,
        const uint4* __restrict__ bfrag,
        const float* __restrict__ cheb_b, const float* __restrict__ fw,
        const float* __restrict__ fb, float* __restrict__ out, int n) {
    int tid = threadIdx.x;
    int lane = tid & 63;
    int wave = tid >> 6;
    int q = lane >> 4, m = lane & 15;
    int node_base = blockIdx.x * 64 + wave * 16;
    int node = node_base + m;
    size_t nd = (node < n) ? (size_t)node : 0;   // clamp; store is guarded

    f32x4 acc[8];
#pragma unroll
    for (int t = 0; t < 8; ++t) acc[t] = (f32x4){0.f, 0.f, 0.f, 0.f};

    const uint4* txs[4] = {tx0, tx1, tx2, tx3};
#pragma unroll
    for (int kk = 0; kk < 8; ++kk) {
        U16 av;
        av.u = txs[kk >> 1][nd * 8 + (kk & 1) * 4 + q];
#pragma unroll
        for (int ht = 0; ht < 8; ++ht) {
            U16 bv;
            bv.u = bfrag[(kk * 8 + ht) * 64 + lane];
            acc[ht] = __builtin_amdgcn_mfma_f32_16x16x32_f16(av.h8, bv.h8, acc[ht], 0, 0, 0);
        }
    }

    float s[4] = {0.f, 0.f, 0.f, 0.f};
#pragma unroll
    for (int ht = 0; ht < 8; ++ht) {
        int h = ht * 16 + m;
        float cb = cheb_b[h];
        float fv = fw[h];
#pragma unroll
        for (int r = 0; r < 4; ++r)
            s[r] = fmaf(tanh_fast(acc[ht][r] + cb), fv, s[r]);
    }
#pragma unroll
    for (int r = 0; r < 4; ++r) {
        for (int msk = 1; msk < 16; msk <<= 1)
            s[r] += __shfl_xor(s[r], msk, 64);
    }
    if (m == 0) {
        float fb0 = fb[0];
#pragma unroll
        for (int r = 0; r < 4; ++r) {
            int o = node_base + q * 4 + r;
            if (o < n) out[o] = s[r] + fb0;
        }
    }
}

extern "C" void kernel_launch(void* const* d_in, const int* in_sizes, int n_in,
                              void* d_out, int out_size, void* d_ws, size_t ws_size,
                              hipStream_t stream) {
    const float* features = (const float*)d_in[0];
    const int*   edge_index = (const int*)d_in[1];
    const float* cheb_w  = (const float*)d_in[2];
    const float* cheb_b  = (const float*)d_in[3];
    const float* final_w = (const float*)d_in[4];
    const float* final_b = (const float*)d_in[5];
    int N = in_sizes[0] / FIN;
    int E = in_sizes[1] / 2;
    const int* row = edge_index;        // edge_index[0, :]
    const int* col = edge_index + E;    // edge_index[1, :]

    char* p = (char*)d_ws;
    auto alloc = [&](size_t bytes) {
        char* r = p;
        p += (bytes + 255) & ~(size_t)255;
        return r;
    };
    int*   deg    = (int*)alloc((size_t)N * 4);
    float* dinv   = (float*)alloc((size_t)N * 4);
    int*   rowptr = (int*)alloc((size_t)(N + 1) * 4);
    int*   cursor = (int*)alloc((size_t)N * 4);
    int*   bsum   = (int*)alloc(1024 * 4);
    int*   col_s  = (int*)alloc((size_t)E * 4);
    uint4* feath  = (uint4*)alloc((size_t)N * FIN * 2);   // unscaled fp16
    uint4* feats  = (uint4*)alloc((size_t)N * FIN * 2);   // dinv-scaled fp16
    uint4* tx1h   = (uint4*)alloc((size_t)N * FIN * 2);
    uint4* tx1s   = (uint4*)alloc((size_t)N * FIN * 2);
    uint4* tx2h   = (uint4*)alloc((size_t)N * FIN * 2);
    uint4* tx2s   = (uint4*)alloc((size_t)N * FIN * 2);
    uint4* tx3h   = (uint4*)alloc((size_t)N * FIN * 2);
    uint4* bfrag  = (uint4*)alloc(4096 * 16);             // 64 KB B fragments

    hipMemsetAsync(deg, 0, (size_t)N * 4, stream);
    count_deg<<<(E + 255) / 256, 256, 0, stream>>>(row, deg, E);
    make_dinv<<<(N + 255) / 256, 256, 0, stream>>>(deg, dinv, N);
    int n8 = N * FIN / 8;
    cvt_feat<<<(n8 + 255) / 256, 256, 0, stream>>>((const float4*)features, dinv,
                                                   feath, feats, n8);
    make_bfrag<<<16, 256, 0, stream>>>(cheb_w, bfrag);
    int nb = (N + 1023) / 1024;
    scan_local<<<nb, 1024, 0, stream>>>(deg, rowptr, bsum, N);
    scan_bsums<<<1, 64, 0, stream>>>(bsum, nb);
    scan_finish<<<(N + 1 + 255) / 256, 256, 0, stream>>>(rowptr, bsum, cursor, N, E);

    // 4 sequential row-striped scatter passes (write locality)
    int eb = (E + 255) / 256;
    int stride = (N + 3) / 4;
    for (int pass = 0; pass < 4; ++pass) {
        int lo = pass * stride;
        int hi = (pass == 3) ? N : lo + stride;
        scatter_pass<<<eb, 256, 0, stream>>>(row, col, cursor, col_s, E, lo, hi);
    }

    int spmm_blocks = (((N + 7) / 8) * 64 + 255) / 256;
    // Tx1 = L_hat @ x
    spmm_g<<<spmm_blocks, 256, 0, stream>>>(rowptr, col_s, feats, nullptr, dinv,
                                            1.f, tx1h, tx1s, N);
    // Tx2 = 2 * L_hat @ Tx1 - Tx0
    spmm_g<<<spmm_blocks, 256, 0, stream>>>(rowptr, col_s, tx1s, feath, dinv,
                                            2.f, tx2h, tx2s, N);
    // Tx3 = 2 * L_hat @ Tx2 - Tx1
    spmm_g<<<spmm_blocks, 256, 0, stream>>>(rowptr, col_s, tx2s, tx1h, dinv,
                                            2.f, tx3h, nullptr, N);

    gemm_mfma<<<(N + 63) / 64, 256, 0, stream>>>(feath, tx1h, tx2h, tx3h, bfrag,
                                                 cheb_b, final_w, final_b,
                                                 (float*)d_out, N);
}